// Round 8
// baseline (58.007 us; speedup 1.0000x reference)
//
#include <hip/hip_runtime.h>
#include <math.h>

#define NB   2
#define NP   4096
#define KNN  32
#define DIMC 128
#define NROWS (NB*NP)          // 8192
#define MTOT  (NB*NP*KNN)      // 262144
#define K2BLOCKS 512           // 16 points each (4 per wave)
#define MAINBLOCKS 512

static constexpr float R2 = 0.04f;

// ---------------- k1: e = feat@W0, g = feat@W1 ----------------
// grid 1024 = 256 rowblk x 4 colblk -> 4 blocks/CU, 16 waves/CU, 4 waves/SIMD.
// Block = 32 rows x 64 cols; thread = 2x4. A-tile (32x128, ld=132) in LDS:
// per-wave ds_read is 4 (even rows) / 4 (odd rows) distinct broadcast addrs on
// distinct bank-quads (8*tr+4*k4 mod 32) -> conflict-free. B from global: 16
// distinct float4 per wave-instr = 256 B segment of the L1-resident 32 KB W
// col-slice. 4 waves/SIMD hide the B-load latency (the round-5/7 killer).
__global__ __launch_bounds__(256) void k1(const float* __restrict__ feat,
                                          const float* __restrict__ Wm,
                                          float* __restrict__ e,
                                          float* __restrict__ g)
{
    __shared__ float sa[32*132];           // 16.9 KB
    const int t      = threadIdx.x;
    const int rowblk = blockIdx.x >> 2;
    const int colblk = blockIdx.x & 3;
    const int cb     = colblk >> 1;        // 0 -> e, 1 -> g
    const int coff   = (colblk & 1) * 64;
    const int row0   = rowblk * 32;
    const int tr     = t >> 4;             // 0..15 -> rows {2tr, 2tr+1}
    const int tc     = t & 15;             // 0..15 -> cols tc*4
    const float* wsrc = Wm + (size_t)cb*128*DIMC + coff;

    // stage A tile: 32x128 f32, coalesced float4
    #pragma unroll
    for (int q = 0; q < 4; ++q) {
        const int fid = q*256 + t;         // 0..1023 float4 slots
        const int r   = fid >> 5;          // 0..31
        const int kq  = fid & 31;          // 0..31
        const float4 v = *(const float4*)(feat + (size_t)(row0 + r)*DIMC + kq*4);
        *(float4*)&sa[r*132 + kq*4] = v;
    }
    __syncthreads();

    float acc[2][4];
    #pragma unroll
    for (int i = 0; i < 2; ++i) { acc[i][0]=0.f; acc[i][1]=0.f; acc[i][2]=0.f; acc[i][3]=0.f; }

    #pragma unroll 2
    for (int k4 = 0; k4 < 32; ++k4) {
        float4 bw[4];
        #pragma unroll
        for (int j = 0; j < 4; ++j)
            bw[j] = *(const float4*)(wsrc + (size_t)(k4*4 + j)*DIMC + tc*4);
        float4 ar[2];
        ar[0] = *(const float4*)&sa[(2*tr    )*132 + k4*4];
        ar[1] = *(const float4*)&sa[(2*tr + 1)*132 + k4*4];
        #pragma unroll
        for (int j = 0; j < 4; ++j) {
            #pragma unroll
            for (int i = 0; i < 2; ++i) {
                const float a = (j==0)?ar[i].x:(j==1)?ar[i].y:(j==2)?ar[i].z:ar[i].w;
                acc[i][0] = fmaf(a, bw[j].x, acc[i][0]);
                acc[i][1] = fmaf(a, bw[j].y, acc[i][1]);
                acc[i][2] = fmaf(a, bw[j].z, acc[i][2]);
                acc[i][3] = fmaf(a, bw[j].w, acc[i][3]);
            }
        }
    }

    float* dst = cb ? g : e;
    #pragma unroll
    for (int i = 0; i < 2; ++i)
        *(float4*)(dst + (size_t)(row0 + 2*tr + i)*DIMC + coff + tc*4) =
            make_float4(acc[i][0], acc[i][1], acc[i][2], acc[i][3]);
}

// ---------------- k2: mask + extract + geo + h (min/max over K) + stat partials ----------------
__global__ __launch_bounds__(256) void k2(const float* __restrict__ xyzp,
                                          const float* __restrict__ e,
                                          const float* __restrict__ g,
                                          const float* __restrict__ Wm,
                                          const float* __restrict__ bbias,
                                          double* __restrict__ spart,
                                          float* __restrict__ hmaxA,
                                          float* __restrict__ hminA,
                                          float* __restrict__ stpartT)
{
    __shared__ float xy[NP*2];                 // 32 KB
    __shared__ int   idxrow[16*KNN];           // 2 KB
    __shared__ float geo[4][2][KNN][8];        // 8 KB
    __shared__ float l1s[8][DIMC];             // 4 KB
    __shared__ float l2s[8][DIMC];             // 4 KB
    __shared__ float swr[8];

    const int bx  = blockIdx.x;
    const int xcd = bx & 7;
    const int pb  = ((xcd >> 2) << 8) + (bx >> 3)*4 + (xcd & 3);  // bijective: batch b -> 4 XCDs
    const int b   = pb >> 8;
    const int p0  = (pb & 255) * 16;

    const int t    = threadIdx.x;
    const int w    = t >> 6;
    const int lane = t & 63;
    const float* xb = xyzp + (size_t)b*NP*4;

    for (int q = t; q < NP; q += 256) {
        const float4 v = *(const float4*)(xb + (size_t)q*4);
        xy[q*2 + 0] = v.x;
        xy[q*2 + 1] = v.y;
    }
    __syncthreads();

    // ---- mask build (contract off to match numpy d2 exactly) ----
    const int pl0 = p0 + w*4;
    unsigned long long wacc[4] = {0ULL, 0ULL, 0ULL, 0ULL};
    {
#pragma clang fp contract(off)
        float xi[4], yi[4];
        #pragma unroll
        for (int p = 0; p < 4; ++p) { xi[p] = xy[(pl0+p)*2]; yi[p] = xy[(pl0+p)*2+1]; }
        for (int c = 0; c < NP/64; ++c) {
            const float2 q = *(const float2*)(xy + (size_t)(c*64 + lane)*2);
            const bool keep = (lane == c);
            #pragma unroll
            for (int p = 0; p < 4; ++p) {
                const float dx = xi[p] - q.x;
                const float dy = yi[p] - q.y;
                const float dx2 = dx*dx;
                const float dy2 = dy*dy;
                const unsigned long long m = __ballot((dx2 + dy2) < R2);
                if (keep) wacc[p] = m;        // lane l keeps word l (j in [64l, 64l+64))
            }
        }
    }

    // ---- extraction: 32 smallest hit indices per point ----
    #pragma unroll
    for (int p = 0; p < 4; ++p) {
        unsigned long long wd = wacc[p];
        const int cnt = __popcll(wd);
        int pre = cnt;
        #pragma unroll
        for (int off = 1; off < 64; off <<= 1) {
            const int tv = __shfl_up(pre, off);
            if (lane >= off) pre += tv;
        }
        const int total = __shfl(pre, 63);
        int slot = pre - cnt;                 // exclusive prefix
        unsigned long long ww = wd;
        while (ww != 0ULL && slot < KNN) {
            const int bpos = __builtin_ctzll(ww);
            idxrow[(w*4 + p)*KNN + slot] = lane*64 + bpos;
            ww &= ww - 1ULL;
            ++slot;
        }
        const int iself = pl0 + p;
        for (int kk = min(total, KNN) + lane; kk < KNN; kk += 64)
            idxrow[(w*4 + p)*KNN + kk] = iself;
    }

    // ---- per-lane channel constants ----
    const int half = lane >> 5;
    const int lq   = lane & 31;
    const int c0   = lq * 4;
    float4 w2r[7];
    #pragma unroll
    for (int r = 0; r < 7; ++r)
        w2r[r] = *(const float4*)(Wm + (size_t)(256 + r)*DIMC + c0);
    const float4 bb4 = *(const float4*)(bbias + c0);

    float s1x=0.f,s1y=0.f,s1z=0.f,s1w=0.f;
    float s2x=0.f,s2y=0.f,s2z=0.f,s2w=0.f;
    float sxacc = 0.f, syacc = 0.f;
    const float* gbb = g + (size_t)b*NP*DIMC + c0;

    for (int rp = 0; rp < 2; ++rp) {
        // geo phase: lane handles pair (row = w*4+rp*2+half, k = lq)
        const int rloc = w*4 + rp*2 + half;
        const int ptl  = p0 + rloc;
        const int j0   = idxrow[rloc*KNN + lq];
        const float4 pj = *(const float4*)(xb + (size_t)j0*4);
        const float4 pi = *(const float4*)(xb + (size_t)ptl*4);
        const float dx = pi.x - pj.x;
        const float dy = pi.y - pj.y;
        const float dz = pi.z - pj.z;
        const float dwv = pi.w - pj.w;
        const float ts  = (dz == 0.f) ? 1e-6f : dz;
        const float rts = __builtin_amdgcn_rcpf(ts);
        const float sxv = dx*rts*640.f;
        const float syv = dy*rts*480.f;
        *(float4*)&geo[w][half][lq][0] = make_float4(dx, dy, dz, dwv);
        *(float4*)&geo[w][half][lq][4] = make_float4(sxv, syv, fabsf(dwv), __int_as_float(j0));
        sxacc += sxv; syacc += syv;
        __builtin_amdgcn_wave_barrier();

        // h phase: this lane's row is the SAME row it just built geo for
        const size_t rowg = (size_t)b*NP + ptl;
        const float4 ee = *(const float4*)(e + rowg*DIMC + c0);
        const float ecx = ee.x + bb4.x, ecy = ee.y + bb4.y;
        const float ecz = ee.z + bb4.z, ecw = ee.w + bb4.w;
        float mxx=-INFINITY,mxy=-INFINITY,mxz=-INFINITY,mxw=-INFINITY;
        float mnx= INFINITY,mny= INFINITY,mnz= INFINITY,mnw= INFINITY;
        #pragma unroll 4
        for (int k = 0; k < KNN; ++k) {
            const float4 g0 = *(const float4*)&geo[w][half][k][0];
            const float4 g1 = *(const float4*)&geo[w][half][k][4];
            const int jj = __float_as_int(g1.w);
            const float4 gg = *(const float4*)(gbb + (size_t)jj*DIMC);

            float h0 = ecx + gg.x;
            h0 = fmaf(g0.x, w2r[0].x, h0); h0 = fmaf(g0.y, w2r[1].x, h0);
            h0 = fmaf(g0.z, w2r[2].x, h0); h0 = fmaf(g0.w, w2r[3].x, h0);
            h0 = fmaf(g1.x, w2r[4].x, h0); h0 = fmaf(g1.y, w2r[5].x, h0);
            h0 = fmaf(g1.z, w2r[6].x, h0);
            mxx = fmaxf(mxx, h0); mnx = fminf(mnx, h0);
            s1x += h0; s2x = fmaf(h0, h0, s2x);

            float h1 = ecy + gg.y;
            h1 = fmaf(g0.x, w2r[0].y, h1); h1 = fmaf(g0.y, w2r[1].y, h1);
            h1 = fmaf(g0.z, w2r[2].y, h1); h1 = fmaf(g0.w, w2r[3].y, h1);
            h1 = fmaf(g1.x, w2r[4].y, h1); h1 = fmaf(g1.y, w2r[5].y, h1);
            h1 = fmaf(g1.z, w2r[6].y, h1);
            mxy = fmaxf(mxy, h1); mny = fminf(mny, h1);
            s1y += h1; s2y = fmaf(h1, h1, s2y);

            float h2 = ecz + gg.z;
            h2 = fmaf(g0.x, w2r[0].z, h2); h2 = fmaf(g0.y, w2r[1].z, h2);
            h2 = fmaf(g0.z, w2r[2].z, h2); h2 = fmaf(g0.w, w2r[3].z, h2);
            h2 = fmaf(g1.x, w2r[4].z, h2); h2 = fmaf(g1.y, w2r[5].z, h2);
            h2 = fmaf(g1.z, w2r[6].z, h2);
            mxz = fmaxf(mxz, h2); mnz = fminf(mnz, h2);
            s1z += h2; s2z = fmaf(h2, h2, s2z);

            float h3 = ecw + gg.w;
            h3 = fmaf(g0.x, w2r[0].w, h3); h3 = fmaf(g0.y, w2r[1].w, h3);
            h3 = fmaf(g0.z, w2r[2].w, h3); h3 = fmaf(g0.w, w2r[3].w, h3);
            h3 = fmaf(g1.x, w2r[4].w, h3); h3 = fmaf(g1.y, w2r[5].w, h3);
            h3 = fmaf(g1.z, w2r[6].w, h3);
            mxw = fmaxf(mxw, h3); mnw = fminf(mnw, h3);
            s1w += h3; s2w = fmaf(h3, h3, s2w);
        }
        *(float4*)(hmaxA + rowg*DIMC + c0) = make_float4(mxx, mxy, mxz, mxw);
        *(float4*)(hminA + rowg*DIMC + c0) = make_float4(mnx, mny, mnz, mnw);
        __builtin_amdgcn_wave_barrier();   // geo reused (overwritten) next rp
    }

    // ---- speed wave-reduce -> per-block double partial ----
    #pragma unroll
    for (int off = 32; off > 0; off >>= 1) {
        sxacc += __shfl_down(sxacc, off);
        syacc += __shfl_down(syacc, off);
    }
    if (lane == 0) { swr[w*2] = sxacc; swr[w*2+1] = syacc; }

    // ---- stat partials ----
    *(float4*)&l1s[w*2 + half][c0] = make_float4(s1x, s1y, s1z, s1w);
    *(float4*)&l2s[w*2 + half][c0] = make_float4(s2x, s2y, s2z, s2w);
    __syncthreads();
    if (t < DIMC) {
        float v = 0.f;
        #pragma unroll
        for (int r = 0; r < 8; ++r) v += l1s[r][t];
        stpartT[(size_t)t*MAINBLOCKS + pb] = v;
    } else {
        const int c = t - DIMC;
        float v = 0.f;
        #pragma unroll
        for (int r = 0; r < 8; ++r) v += l2s[r][c];
        stpartT[(size_t)(DIMC + c)*MAINBLOCKS + pb] = v;
    }
    if (t == 0) {
        const double s0 = ((double)swr[0] + (double)swr[2]) + ((double)swr[4] + (double)swr[6]);
        const double s1 = ((double)swr[1] + (double)swr[3]) + ((double)swr[5] + (double)swr[7]);
        spart[(size_t)pb*2 + 0] = s0;
        spart[(size_t)pb*2 + 1] = s1;
    }
}

// ---------------- kE: stat + mean-speed reduce, per-batch affine coefficients ----------------
__global__ __launch_bounds__(256) void kE(const float* __restrict__ stpartT,
                                          const double* __restrict__ spart,
                                          const float* __restrict__ Wm,
                                          const float* __restrict__ gamma,
                                          const float* __restrict__ beta,
                                          float* __restrict__ abuf,
                                          float* __restrict__ dbuf2)
{
    __shared__ double red[256][8];   // 16 KB
    const int c = blockIdx.x;        // 0..127
    const int t = threadIdx.x;

    red[t][0] = spart[(size_t)t*2];            // sx batch0
    red[t][1] = spart[(size_t)t*2 + 1];        // sy batch0
    red[t][2] = spart[(size_t)(t+256)*2];      // sx batch1
    red[t][3] = spart[(size_t)(t+256)*2 + 1];  // sy batch1
    red[t][4] = (double)stpartT[(size_t)c*MAINBLOCKS + t];                    // S1 b0
    red[t][5] = (double)stpartT[(size_t)c*MAINBLOCKS + 256 + t];              // S1 b1
    red[t][6] = (double)stpartT[(size_t)(c + DIMC)*MAINBLOCKS + t];           // S2 b0
    red[t][7] = (double)stpartT[(size_t)(c + DIMC)*MAINBLOCKS + 256 + t];     // S2 b1
    __syncthreads();
    for (int st = 128; st > 0; st >>= 1) {
        if (t < st) {
            #pragma unroll
            for (int q = 0; q < 8; ++q) red[t][q] += red[t+st][q];
        }
        __syncthreads();
    }
    if (t == 0) {
        const double NKd = (double)(NP*KNN);
        const float ms0x = (float)(red[0][0] / NKd);
        const float ms0y = (float)(red[0][1] / NKd);
        const float ms1x = (float)(red[0][2] / NKd);
        const float ms1y = (float)(red[0][3] / NKd);
        const float wx = Wm[263*DIMC + c];
        const float wy = Wm[264*DIMC + c];
        const double cb0 = (double)fmaf(ms0x, wx, ms0y*wy);
        const double cb1 = (double)fmaf(ms1x, wx, ms1y*wy);
        const double s1b0 = red[0][4], s1b1 = red[0][5];
        const double s2b0 = red[0][6], s2b1 = red[0][7];
        const double M  = (double)MTOT;
        const double S1 = s1b0 + s1b1 + NKd*(cb0 + cb1);
        const double S2 = (s2b0 + 2.0*cb0*s1b0 + NKd*cb0*cb0)
                        + (s2b1 + 2.0*cb1*s1b1 + NKd*cb1*cb1);
        const double mu  = S1 / M;
        const double var = S2 / M - mu*mu;
        const double inv = 1.0 / sqrt(var + 1e-5);
        const double a  = (double)gamma[c] * inv;
        const double db = (double)beta[c] - mu*a;
        abuf[c] = (float)a;
        dbuf2[c]        = (float)(db + cb0*a);
        dbuf2[DIMC + c] = (float)(db + cb1*a);
    }
}

// ---------------- kF: normalize + relu on the pre-reduced K-extremes ----------------
__global__ __launch_bounds__(256) void kF(const float* __restrict__ hmaxA,
                                          const float* __restrict__ hminA,
                                          const float* __restrict__ abuf,
                                          const float* __restrict__ dbuf2,
                                          float* __restrict__ out)
{
    const int gid = blockIdx.x*256 + threadIdx.x;
    const int row = gid >> 6;
    const int c0  = (gid & 63)*2;
    const int b   = row >> 12;
    const size_t off = (size_t)row*DIMC + c0;
    const float2 mx = *(const float2*)(hmaxA + off);
    const float2 mn = *(const float2*)(hminA + off);
    const float a0 = abuf[c0],  a1 = abuf[c0+1];
    const float d0 = dbuf2[b*DIMC + c0], d1 = dbuf2[b*DIMC + c0 + 1];
    const float h0 = (a0 >= 0.f) ? mx.x : mn.x;
    const float h1 = (a1 >= 0.f) ? mx.y : mn.y;
    float2 o;
    o.x = fmaxf(fmaf(h0, a0, d0), 0.0f);
    o.y = fmaxf(fmaf(h1, a1, d1), 0.0f);
    *(float2*)(out + off) = o;
}

extern "C" void kernel_launch(void* const* d_in, const int* in_sizes, int n_in,
                              void* d_out, int out_size, void* d_ws, size_t ws_size,
                              hipStream_t stream)
{
    const float* xyzp  = (const float*)d_in[0];
    const float* feat  = (const float*)d_in[1];
    const float* Wm    = (const float*)d_in[2];
    const float* bbias = (const float*)d_in[3];
    const float* gamma = (const float*)d_in[4];
    const float* beta  = (const float*)d_in[5];

    char* ws = (char*)d_ws;
    const size_t MB = 1u << 20;
    float*  g       = (float*) (ws + 1*MB);          // 4 MB
    float*  e       = (float*) (ws + 5*MB);          // 4 MB
    float*  hmaxA   = (float*) (ws + 9*MB);          // 4 MB
    float*  hminA   = (float*) (ws + 13*MB);         // 4 MB
    double* spart   = (double*)(ws + 17*MB);         // 8 KB (512 x double2)
    float*  abuf    = (float*) (ws + 17*MB + 65536); // 512 B
    float*  dbuf2   = (float*) (ws + 17*MB + 66560); // 1 KB
    float*  stpartT = (float*) (ws + 18*MB);         // 512 KB (256 x 512)

    k1 <<<1024, 256, 0, stream>>>(feat, Wm, e, g);
    k2 <<<K2BLOCKS, 256, 0, stream>>>(xyzp, e, g, Wm, bbias, spart, hmaxA, hminA, stpartT);
    kE <<<DIMC, 256, 0, stream>>>(stpartT, spart, Wm, gamma, beta, abuf, dbuf2);
    kF <<<(NROWS*64)/256, 256, 0, stream>>>(hmaxA, hminA, abuf, dbuf2, (float*)d_out);
}

// Round 9
// 53.297 us; speedup vs baseline: 1.0884x; 1.0884x over previous
//
#include <hip/hip_runtime.h>
#include <math.h>

#define NB   2
#define NP   4096
#define KNN  32
#define DIMC 128
#define NROWS (NB*NP)          // 8192
#define MTOT  (NB*NP*KNN)      // 262144
#define K2BLOCKS 512           // 16 points each (4 per wave)
#define MAINBLOCKS 512

static constexpr float R2 = 0.04f;

// ---------------- k1: e = feat@W0, g = feat@W1  (scalar-A / coalesced-B) ----------------
// Lane = output column; B = Wm[k][c0+lane] -> coalesced 256B b32 (L1-hot, reused
// by all row-waves); A = feat[row][k] wave-uniform -> s_load_dwordx4 on the SMEM
// pipe (row0 made provably uniform via readfirstlane). Inner loop: v_fma(v,s,v),
// ZERO LDS, zero strided VMEM. Wave = 8 rows x 64 cols; grid 4096 waves = 1024
// blocks -> 4 blocks/CU, 4 waves/SIMD. VALU wall ~3.4 us chip-wide.
__global__ __launch_bounds__(256) void k1(const float* __restrict__ feat,
                                          const float* __restrict__ Wm,
                                          float* __restrict__ e,
                                          float* __restrict__ g)
{
    const int t    = threadIdx.x;
    const int lane = t & 63;
    const int wid  = __builtin_amdgcn_readfirstlane(t >> 6);
    const int wgl  = blockIdx.x * 4 + wid;     // 0..4095
    const int row0 = (wgl >> 2) * 8;           // 1024 row-groups x 8 rows
    const int cg   = wgl & 3;                  // col-group
    const int wbase = (cg >> 1) * 128;         // 0 -> e-slice of W, 128 -> g-slice
    const int c0    = (cg & 1) * 64;

    const float* __restrict__ fptr = feat + (size_t)row0 * DIMC;
    const float* __restrict__ wptr = Wm + (size_t)wbase * DIMC + c0 + lane;

    float acc[8];
    #pragma unroll
    for (int r = 0; r < 8; ++r) acc[r] = 0.f;

    #pragma unroll 2
    for (int k4 = 0; k4 < 32; ++k4) {
        float bv[4];
        #pragma unroll
        for (int j = 0; j < 4; ++j)
            bv[j] = wptr[(size_t)(k4*4 + j)*DIMC];          // coalesced b32
        float4 as[8];
        #pragma unroll
        for (int r = 0; r < 8; ++r)
            as[r] = *(const float4*)(fptr + (size_t)r*DIMC + k4*4);   // s_load_dwordx4
        #pragma unroll
        for (int r = 0; r < 8; ++r) {
            acc[r] = fmaf(as[r].x, bv[0], acc[r]);
            acc[r] = fmaf(as[r].y, bv[1], acc[r]);
            acc[r] = fmaf(as[r].z, bv[2], acc[r]);
            acc[r] = fmaf(as[r].w, bv[3], acc[r]);
        }
    }

    float* dst = (cg >> 1) ? g : e;
    #pragma unroll
    for (int r = 0; r < 8; ++r)
        dst[(size_t)(row0 + r)*DIMC + c0 + lane] = acc[r];  // coalesced b32
}

// ---------------- k2: mask + extract + geo + h (min/max over K) + stat partials ----------------
__global__ __launch_bounds__(256) void k2(const float* __restrict__ xyzp,
                                          const float* __restrict__ e,
                                          const float* __restrict__ g,
                                          const float* __restrict__ Wm,
                                          const float* __restrict__ bbias,
                                          double* __restrict__ spart,
                                          float* __restrict__ hmaxA,
                                          float* __restrict__ hminA,
                                          float* __restrict__ stpartT)
{
    __shared__ float xy[NP*2];                 // 32 KB
    __shared__ int   idxrow[16*KNN];           // 2 KB
    __shared__ float geo[4][2][KNN][8];        // 8 KB
    __shared__ float l1s[8][DIMC];             // 4 KB
    __shared__ float l2s[8][DIMC];             // 4 KB
    __shared__ float swr[8];

    const int bx  = blockIdx.x;
    const int xcd = bx & 7;
    const int pb  = ((xcd >> 2) << 8) + (bx >> 3)*4 + (xcd & 3);  // bijective: batch b -> 4 XCDs
    const int b   = pb >> 8;
    const int p0  = (pb & 255) * 16;

    const int t    = threadIdx.x;
    const int w    = t >> 6;
    const int lane = t & 63;
    const float* xb = xyzp + (size_t)b*NP*4;

    for (int q = t; q < NP; q += 256) {
        const float4 v = *(const float4*)(xb + (size_t)q*4);
        xy[q*2 + 0] = v.x;
        xy[q*2 + 1] = v.y;
    }
    __syncthreads();

    // ---- mask build (contract off to match numpy d2 exactly) ----
    const int pl0 = p0 + w*4;
    unsigned long long wacc[4] = {0ULL, 0ULL, 0ULL, 0ULL};
    {
#pragma clang fp contract(off)
        float xi[4], yi[4];
        #pragma unroll
        for (int p = 0; p < 4; ++p) { xi[p] = xy[(pl0+p)*2]; yi[p] = xy[(pl0+p)*2+1]; }
        for (int c = 0; c < NP/64; ++c) {
            const float2 q = *(const float2*)(xy + (size_t)(c*64 + lane)*2);
            const bool keep = (lane == c);
            #pragma unroll
            for (int p = 0; p < 4; ++p) {
                const float dx = xi[p] - q.x;
                const float dy = yi[p] - q.y;
                const float dx2 = dx*dx;
                const float dy2 = dy*dy;
                const unsigned long long m = __ballot((dx2 + dy2) < R2);
                if (keep) wacc[p] = m;        // lane l keeps word l (j in [64l, 64l+64))
            }
        }
    }

    // ---- extraction: 32 smallest hit indices per point ----
    #pragma unroll
    for (int p = 0; p < 4; ++p) {
        unsigned long long wd = wacc[p];
        const int cnt = __popcll(wd);
        int pre = cnt;
        #pragma unroll
        for (int off = 1; off < 64; off <<= 1) {
            const int tv = __shfl_up(pre, off);
            if (lane >= off) pre += tv;
        }
        const int total = __shfl(pre, 63);
        int slot = pre - cnt;                 // exclusive prefix
        unsigned long long ww = wd;
        while (ww != 0ULL && slot < KNN) {
            const int bpos = __builtin_ctzll(ww);
            idxrow[(w*4 + p)*KNN + slot] = lane*64 + bpos;
            ww &= ww - 1ULL;
            ++slot;
        }
        const int iself = pl0 + p;
        for (int kk = min(total, KNN) + lane; kk < KNN; kk += 64)
            idxrow[(w*4 + p)*KNN + kk] = iself;
    }

    // ---- per-lane channel constants ----
    const int half = lane >> 5;
    const int lq   = lane & 31;
    const int c0   = lq * 4;
    float4 w2r[7];
    #pragma unroll
    for (int r = 0; r < 7; ++r)
        w2r[r] = *(const float4*)(Wm + (size_t)(256 + r)*DIMC + c0);
    const float4 bb4 = *(const float4*)(bbias + c0);

    float s1x=0.f,s1y=0.f,s1z=0.f,s1w=0.f;
    float s2x=0.f,s2y=0.f,s2z=0.f,s2w=0.f;
    float sxacc = 0.f, syacc = 0.f;
    const float* gbb = g + (size_t)b*NP*DIMC + c0;

    for (int rp = 0; rp < 2; ++rp) {
        // geo phase: lane handles pair (row = w*4+rp*2+half, k = lq)
        const int rloc = w*4 + rp*2 + half;
        const int ptl  = p0 + rloc;
        const int j0   = idxrow[rloc*KNN + lq];
        const float4 pj = *(const float4*)(xb + (size_t)j0*4);
        const float4 pi = *(const float4*)(xb + (size_t)ptl*4);
        const float dx = pi.x - pj.x;
        const float dy = pi.y - pj.y;
        const float dz = pi.z - pj.z;
        const float dwv = pi.w - pj.w;
        const float ts  = (dz == 0.f) ? 1e-6f : dz;
        const float rts = __builtin_amdgcn_rcpf(ts);
        const float sxv = dx*rts*640.f;
        const float syv = dy*rts*480.f;
        *(float4*)&geo[w][half][lq][0] = make_float4(dx, dy, dz, dwv);
        *(float4*)&geo[w][half][lq][4] = make_float4(sxv, syv, fabsf(dwv), __int_as_float(j0));
        sxacc += sxv; syacc += syv;
        __builtin_amdgcn_wave_barrier();

        // h phase: this lane's row is the SAME row it just built geo for
        const size_t rowg = (size_t)b*NP + ptl;
        const float4 ee = *(const float4*)(e + rowg*DIMC + c0);
        const float ecx = ee.x + bb4.x, ecy = ee.y + bb4.y;
        const float ecz = ee.z + bb4.z, ecw = ee.w + bb4.w;
        float mxx=-INFINITY,mxy=-INFINITY,mxz=-INFINITY,mxw=-INFINITY;
        float mnx= INFINITY,mny= INFINITY,mnz= INFINITY,mnw= INFINITY;
        #pragma unroll 4
        for (int k = 0; k < KNN; ++k) {
            const float4 g0 = *(const float4*)&geo[w][half][k][0];
            const float4 g1 = *(const float4*)&geo[w][half][k][4];
            const int jj = __float_as_int(g1.w);
            const float4 gg = *(const float4*)(gbb + (size_t)jj*DIMC);

            float h0 = ecx + gg.x;
            h0 = fmaf(g0.x, w2r[0].x, h0); h0 = fmaf(g0.y, w2r[1].x, h0);
            h0 = fmaf(g0.z, w2r[2].x, h0); h0 = fmaf(g0.w, w2r[3].x, h0);
            h0 = fmaf(g1.x, w2r[4].x, h0); h0 = fmaf(g1.y, w2r[5].x, h0);
            h0 = fmaf(g1.z, w2r[6].x, h0);
            mxx = fmaxf(mxx, h0); mnx = fminf(mnx, h0);
            s1x += h0; s2x = fmaf(h0, h0, s2x);

            float h1 = ecy + gg.y;
            h1 = fmaf(g0.x, w2r[0].y, h1); h1 = fmaf(g0.y, w2r[1].y, h1);
            h1 = fmaf(g0.z, w2r[2].y, h1); h1 = fmaf(g0.w, w2r[3].y, h1);
            h1 = fmaf(g1.x, w2r[4].y, h1); h1 = fmaf(g1.y, w2r[5].y, h1);
            h1 = fmaf(g1.z, w2r[6].y, h1);
            mxy = fmaxf(mxy, h1); mny = fminf(mny, h1);
            s1y += h1; s2y = fmaf(h1, h1, s2y);

            float h2 = ecz + gg.z;
            h2 = fmaf(g0.x, w2r[0].z, h2); h2 = fmaf(g0.y, w2r[1].z, h2);
            h2 = fmaf(g0.z, w2r[2].z, h2); h2 = fmaf(g0.w, w2r[3].z, h2);
            h2 = fmaf(g1.x, w2r[4].z, h2); h2 = fmaf(g1.y, w2r[5].z, h2);
            h2 = fmaf(g1.z, w2r[6].z, h2);
            mxz = fmaxf(mxz, h2); mnz = fminf(mnz, h2);
            s1z += h2; s2z = fmaf(h2, h2, s2z);

            float h3 = ecw + gg.w;
            h3 = fmaf(g0.x, w2r[0].w, h3); h3 = fmaf(g0.y, w2r[1].w, h3);
            h3 = fmaf(g0.z, w2r[2].w, h3); h3 = fmaf(g0.w, w2r[3].w, h3);
            h3 = fmaf(g1.x, w2r[4].w, h3); h3 = fmaf(g1.y, w2r[5].w, h3);
            h3 = fmaf(g1.z, w2r[6].w, h3);
            mxw = fmaxf(mxw, h3); mnw = fminf(mnw, h3);
            s1w += h3; s2w = fmaf(h3, h3, s2w);
        }
        *(float4*)(hmaxA + rowg*DIMC + c0) = make_float4(mxx, mxy, mxz, mxw);
        *(float4*)(hminA + rowg*DIMC + c0) = make_float4(mnx, mny, mnz, mnw);
        __builtin_amdgcn_wave_barrier();   // geo reused (overwritten) next rp
    }

    // ---- speed wave-reduce -> per-block double partial ----
    #pragma unroll
    for (int off = 32; off > 0; off >>= 1) {
        sxacc += __shfl_down(sxacc, off);
        syacc += __shfl_down(syacc, off);
    }
    if (lane == 0) { swr[w*2] = sxacc; swr[w*2+1] = syacc; }

    // ---- stat partials ----
    *(float4*)&l1s[w*2 + half][c0] = make_float4(s1x, s1y, s1z, s1w);
    *(float4*)&l2s[w*2 + half][c0] = make_float4(s2x, s2y, s2z, s2w);
    __syncthreads();
    if (t < DIMC) {
        float v = 0.f;
        #pragma unroll
        for (int r = 0; r < 8; ++r) v += l1s[r][t];
        stpartT[(size_t)t*MAINBLOCKS + pb] = v;
    } else {
        const int c = t - DIMC;
        float v = 0.f;
        #pragma unroll
        for (int r = 0; r < 8; ++r) v += l2s[r][c];
        stpartT[(size_t)(DIMC + c)*MAINBLOCKS + pb] = v;
    }
    if (t == 0) {
        const double s0 = ((double)swr[0] + (double)swr[2]) + ((double)swr[4] + (double)swr[6]);
        const double s1 = ((double)swr[1] + (double)swr[3]) + ((double)swr[5] + (double)swr[7]);
        spart[(size_t)pb*2 + 0] = s0;
        spart[(size_t)pb*2 + 1] = s1;
    }
}

// ---------------- kE: stat + mean-speed reduce, per-batch affine coefficients ----------------
__global__ __launch_bounds__(256) void kE(const float* __restrict__ stpartT,
                                          const double* __restrict__ spart,
                                          const float* __restrict__ Wm,
                                          const float* __restrict__ gamma,
                                          const float* __restrict__ beta,
                                          float* __restrict__ abuf,
                                          float* __restrict__ dbuf2)
{
    __shared__ double red[256][8];   // 16 KB
    const int c = blockIdx.x;        // 0..127
    const int t = threadIdx.x;

    red[t][0] = spart[(size_t)t*2];            // sx batch0
    red[t][1] = spart[(size_t)t*2 + 1];        // sy batch0
    red[t][2] = spart[(size_t)(t+256)*2];      // sx batch1
    red[t][3] = spart[(size_t)(t+256)*2 + 1];  // sy batch1
    red[t][4] = (double)stpartT[(size_t)c*MAINBLOCKS + t];                    // S1 b0
    red[t][5] = (double)stpartT[(size_t)c*MAINBLOCKS + 256 + t];              // S1 b1
    red[t][6] = (double)stpartT[(size_t)(c + DIMC)*MAINBLOCKS + t];           // S2 b0
    red[t][7] = (double)stpartT[(size_t)(c + DIMC)*MAINBLOCKS + 256 + t];     // S2 b1
    __syncthreads();
    for (int st = 128; st > 0; st >>= 1) {
        if (t < st) {
            #pragma unroll
            for (int q = 0; q < 8; ++q) red[t][q] += red[t+st][q];
        }
        __syncthreads();
    }
    if (t == 0) {
        const double NKd = (double)(NP*KNN);
        const float ms0x = (float)(red[0][0] / NKd);
        const float ms0y = (float)(red[0][1] / NKd);
        const float ms1x = (float)(red[0][2] / NKd);
        const float ms1y = (float)(red[0][3] / NKd);
        const float wx = Wm[263*DIMC + c];
        const float wy = Wm[264*DIMC + c];
        const double cb0 = (double)fmaf(ms0x, wx, ms0y*wy);
        const double cb1 = (double)fmaf(ms1x, wx, ms1y*wy);
        const double s1b0 = red[0][4], s1b1 = red[0][5];
        const double s2b0 = red[0][6], s2b1 = red[0][7];
        const double M  = (double)MTOT;
        const double S1 = s1b0 + s1b1 + NKd*(cb0 + cb1);
        const double S2 = (s2b0 + 2.0*cb0*s1b0 + NKd*cb0*cb0)
                        + (s2b1 + 2.0*cb1*s1b1 + NKd*cb1*cb1);
        const double mu  = S1 / M;
        const double var = S2 / M - mu*mu;
        const double inv = 1.0 / sqrt(var + 1e-5);
        const double a  = (double)gamma[c] * inv;
        const double db = (double)beta[c] - mu*a;
        abuf[c] = (float)a;
        dbuf2[c]        = (float)(db + cb0*a);
        dbuf2[DIMC + c] = (float)(db + cb1*a);
    }
}

// ---------------- kF: normalize + relu on the pre-reduced K-extremes ----------------
__global__ __launch_bounds__(256) void kF(const float* __restrict__ hmaxA,
                                          const float* __restrict__ hminA,
                                          const float* __restrict__ abuf,
                                          const float* __restrict__ dbuf2,
                                          float* __restrict__ out)
{
    const int gid = blockIdx.x*256 + threadIdx.x;
    const int row = gid >> 6;
    const int c0  = (gid & 63)*2;
    const int b   = row >> 12;
    const size_t off = (size_t)row*DIMC + c0;
    const float2 mx = *(const float2*)(hmaxA + off);
    const float2 mn = *(const float2*)(hminA + off);
    const float a0 = abuf[c0],  a1 = abuf[c0+1];
    const float d0 = dbuf2[b*DIMC + c0], d1 = dbuf2[b*DIMC + c0 + 1];
    const float h0 = (a0 >= 0.f) ? mx.x : mn.x;
    const float h1 = (a1 >= 0.f) ? mx.y : mn.y;
    float2 o;
    o.x = fmaxf(fmaf(h0, a0, d0), 0.0f);
    o.y = fmaxf(fmaf(h1, a1, d1), 0.0f);
    *(float2*)(out + off) = o;
}

extern "C" void kernel_launch(void* const* d_in, const int* in_sizes, int n_in,
                              void* d_out, int out_size, void* d_ws, size_t ws_size,
                              hipStream_t stream)
{
    const float* xyzp  = (const float*)d_in[0];
    const float* feat  = (const float*)d_in[1];
    const float* Wm    = (const float*)d_in[2];
    const float* bbias = (const float*)d_in[3];
    const float* gamma = (const float*)d_in[4];
    const float* beta  = (const float*)d_in[5];

    char* ws = (char*)d_ws;
    const size_t MB = 1u << 20;
    float*  g       = (float*) (ws + 1*MB);          // 4 MB
    float*  e       = (float*) (ws + 5*MB);          // 4 MB
    float*  hmaxA   = (float*) (ws + 9*MB);          // 4 MB
    float*  hminA   = (float*) (ws + 13*MB);         // 4 MB
    double* spart   = (double*)(ws + 17*MB);         // 8 KB (512 x double2)
    float*  abuf    = (float*) (ws + 17*MB + 65536); // 512 B
    float*  dbuf2   = (float*) (ws + 17*MB + 66560); // 1 KB
    float*  stpartT = (float*) (ws + 18*MB);         // 512 KB (256 x 512)

    k1 <<<1024, 256, 0, stream>>>(feat, Wm, e, g);
    k2 <<<K2BLOCKS, 256, 0, stream>>>(xyzp, e, g, Wm, bbias, spart, hmaxA, hminA, stpartT);
    kE <<<DIMC, 256, 0, stream>>>(stpartT, spart, Wm, gamma, beta, abuf, dbuf2);
    kF <<<(NROWS*64)/256, 256, 0, stream>>>(hmaxA, hminA, abuf, dbuf2, (float*)d_out);
}

// Round 10
// 50.096 us; speedup vs baseline: 1.1579x; 1.0639x over previous
//
#include <hip/hip_runtime.h>
#include <math.h>

#define NB   2
#define NP   4096
#define KNN  32
#define DIMC 128
#define NROWS (NB*NP)          // 8192
#define MTOT  (NB*NP*KNN)      // 262144
#define K2BLOCKS 512           // 16 points each (4 per wave)
#define MAINBLOCKS 512

static constexpr float R2 = 0.04f;

typedef short bf16x8 __attribute__((ext_vector_type(8)));   // 8 bf16 (4 VGPRs)
typedef float f32x4  __attribute__((ext_vector_type(4)));   // MFMA accumulator

__device__ __forceinline__ unsigned short f2bf(float f) {   // RNE bf16 round
    unsigned u = __float_as_uint(f);
    return (unsigned short)((u + 0x7FFFu + ((u >> 16) & 1u)) >> 16);
}

// ---------------- kC: pack feat and W into bf16 MFMA-fragment order ----------------
// Fragment layout (16x16x32): A: lane l holds A[l&15][(l>>4)*8+j]; B: lane l holds
// B[(l>>4)*8+j][l&15]. Slot s = tile*256 + ks*64 + lane -> 16B (8 bf16).
// Wc[k][c] = Wm[(c>>7)*128 + k][c&127]  (cols 0..127 -> W0/e, 128..255 -> W1/g).
__global__ __launch_bounds__(256) void kC(const float* __restrict__ feat,
                                          const float* __restrict__ Wm,
                                          uint4* __restrict__ featb,
                                          uint4* __restrict__ Wb)
{
    const int bx = blockIdx.x;
    if (bx < 512) {                       // feat: 512 row-tiles x 4 ks x 64 lanes
        const int s  = bx*256 + threadIdx.x;
        const int l  = s & 63;
        const int ks = (s >> 6) & 3;
        const int rt = s >> 8;
        const int row = rt*16 + (l & 15);
        const int kb  = ks*32 + ((l >> 4) << 3);
        const float4 v0 = *(const float4*)(feat + (size_t)row*DIMC + kb);
        const float4 v1 = *(const float4*)(feat + (size_t)row*DIMC + kb + 4);
        uint4 o;
        o.x = (unsigned)f2bf(v0.x) | ((unsigned)f2bf(v0.y) << 16);
        o.y = (unsigned)f2bf(v0.z) | ((unsigned)f2bf(v0.w) << 16);
        o.z = (unsigned)f2bf(v1.x) | ((unsigned)f2bf(v1.y) << 16);
        o.w = (unsigned)f2bf(v1.z) | ((unsigned)f2bf(v1.w) << 16);
        featb[s] = o;                     // coalesced 16B/lane
    } else {                              // W: 16 col-tiles x 4 ks x 64 lanes
        const int s2 = (bx - 512)*256 + threadIdx.x;   // 0..4095
        const int l  = s2 & 63;
        const int ks = (s2 >> 6) & 3;
        const int ct = s2 >> 8;
        const int c  = ct*16 + (l & 15);
        const int kb = ks*32 + ((l >> 4) << 3);
        const float* src = Wm + (size_t)((c >> 7)*128 + kb)*DIMC + (c & 127);
        unsigned short b[8];
        #pragma unroll
        for (int j = 0; j < 8; ++j) b[j] = f2bf(src[(size_t)j*DIMC]);
        uint4 o;
        o.x = (unsigned)b[0] | ((unsigned)b[1] << 16);
        o.y = (unsigned)b[2] | ((unsigned)b[3] << 16);
        o.z = (unsigned)b[4] | ((unsigned)b[5] << 16);
        o.w = (unsigned)b[6] | ((unsigned)b[7] << 16);
        Wb[s2] = o;
    }
}

// ---------------- k1m: e|g = feat @ [W0|W1] via MFMA bf16 ----------------
// Grid 512: block = 16 rows x 256 cols; wave w covers cols w*64..w*64+63
// (4 D-tiles), K=128 = 4 MFMA steps per tile. All loads coalesced b128 from
// pre-packed fragments; no LDS. D layout (m89-verified): col=lane&15,
// row=(lane>>4)*4+reg.
__global__ __launch_bounds__(256) void k1m(const bf16x8* __restrict__ featb,
                                           const bf16x8* __restrict__ Wb,
                                           float* __restrict__ e,
                                           float* __restrict__ g)
{
    const int t    = threadIdx.x;
    const int w    = t >> 6;
    const int lane = t & 63;
    const int rt   = blockIdx.x;          // row-tile: rows rt*16..rt*16+15

    bf16x8 af[4];
    #pragma unroll
    for (int ks = 0; ks < 4; ++ks)
        af[ks] = featb[(size_t)(rt*4 + ks)*64 + lane];

    #pragma unroll
    for (int ct = 0; ct < 4; ++ct) {
        const int ctg = w*4 + ct;         // global col-tile 0..15
        f32x4 acc = {0.f, 0.f, 0.f, 0.f};
        #pragma unroll
        for (int ks = 0; ks < 4; ++ks) {
            const bf16x8 bb = Wb[(size_t)(ctg*4 + ks)*64 + lane];
            acc = __builtin_amdgcn_mfma_f32_16x16x32_bf16(af[ks], bb, acc, 0, 0, 0);
        }
        const int cg = ctg*16 + (lane & 15);          // global col 0..255 (wave-uniform tile)
        float* dst = (cg < 128) ? e : g;
        const int cc = cg & 127;
        const int r0 = (lane >> 4) * 4;
        #pragma unroll
        for (int r = 0; r < 4; ++r)
            dst[(size_t)(rt*16 + r0 + r)*DIMC + cc] = acc[r];
    }
}

// ---------------- k2: mask + extract + geo + h (min/max over K) + stat partials ----------------
__global__ __launch_bounds__(256) void k2(const float* __restrict__ xyzp,
                                          const float* __restrict__ e,
                                          const float* __restrict__ g,
                                          const float* __restrict__ Wm,
                                          const float* __restrict__ bbias,
                                          double* __restrict__ spart,
                                          float* __restrict__ hmaxA,
                                          float* __restrict__ hminA,
                                          float* __restrict__ stpartT)
{
    __shared__ float xy[NP*2];                 // 32 KB
    __shared__ int   idxrow[16*KNN];           // 2 KB
    __shared__ float geo[4][2][KNN][8];        // 8 KB
    __shared__ float l1s[8][DIMC];             // 4 KB
    __shared__ float l2s[8][DIMC];             // 4 KB
    __shared__ float swr[8];

    const int bx  = blockIdx.x;
    const int xcd = bx & 7;
    const int pb  = ((xcd >> 2) << 8) + (bx >> 3)*4 + (xcd & 3);  // bijective: batch b -> 4 XCDs
    const int b   = pb >> 8;
    const int p0  = (pb & 255) * 16;

    const int t    = threadIdx.x;
    const int w    = t >> 6;
    const int lane = t & 63;
    const float* xb = xyzp + (size_t)b*NP*4;

    for (int q = t; q < NP; q += 256) {
        const float4 v = *(const float4*)(xb + (size_t)q*4);
        xy[q*2 + 0] = v.x;
        xy[q*2 + 1] = v.y;
    }
    __syncthreads();

    // ---- mask build (contract off to match numpy d2 exactly) ----
    const int pl0 = p0 + w*4;
    unsigned long long wacc[4] = {0ULL, 0ULL, 0ULL, 0ULL};
    {
#pragma clang fp contract(off)
        float xi[4], yi[4];
        #pragma unroll
        for (int p = 0; p < 4; ++p) { xi[p] = xy[(pl0+p)*2]; yi[p] = xy[(pl0+p)*2+1]; }
        for (int c = 0; c < NP/64; ++c) {
            const float2 q = *(const float2*)(xy + (size_t)(c*64 + lane)*2);
            const bool keep = (lane == c);
            #pragma unroll
            for (int p = 0; p < 4; ++p) {
                const float dx = xi[p] - q.x;
                const float dy = yi[p] - q.y;
                const float dx2 = dx*dx;
                const float dy2 = dy*dy;
                const unsigned long long m = __ballot((dx2 + dy2) < R2);
                if (keep) wacc[p] = m;        // lane l keeps word l (j in [64l, 64l+64))
            }
        }
    }

    // ---- extraction: 32 smallest hit indices per point ----
    #pragma unroll
    for (int p = 0; p < 4; ++p) {
        unsigned long long wd = wacc[p];
        const int cnt = __popcll(wd);
        int pre = cnt;
        #pragma unroll
        for (int off = 1; off < 64; off <<= 1) {
            const int tv = __shfl_up(pre, off);
            if (lane >= off) pre += tv;
        }
        const int total = __shfl(pre, 63);
        int slot = pre - cnt;                 // exclusive prefix
        unsigned long long ww = wd;
        while (ww != 0ULL && slot < KNN) {
            const int bpos = __builtin_ctzll(ww);
            idxrow[(w*4 + p)*KNN + slot] = lane*64 + bpos;
            ww &= ww - 1ULL;
            ++slot;
        }
        const int iself = pl0 + p;
        for (int kk = min(total, KNN) + lane; kk < KNN; kk += 64)
            idxrow[(w*4 + p)*KNN + kk] = iself;
    }

    // ---- per-lane channel constants ----
    const int half = lane >> 5;
    const int lq   = lane & 31;
    const int c0   = lq * 4;
    float4 w2r[7];
    #pragma unroll
    for (int r = 0; r < 7; ++r)
        w2r[r] = *(const float4*)(Wm + (size_t)(256 + r)*DIMC + c0);
    const float4 bb4 = *(const float4*)(bbias + c0);

    float s1x=0.f,s1y=0.f,s1z=0.f,s1w=0.f;
    float s2x=0.f,s2y=0.f,s2z=0.f,s2w=0.f;
    float sxacc = 0.f, syacc = 0.f;
    const float* gbb = g + (size_t)b*NP*DIMC + c0;

    for (int rp = 0; rp < 2; ++rp) {
        // geo phase: lane handles pair (row = w*4+rp*2+half, k = lq)
        const int rloc = w*4 + rp*2 + half;
        const int ptl  = p0 + rloc;
        const int j0   = idxrow[rloc*KNN + lq];
        const float4 pj = *(const float4*)(xb + (size_t)j0*4);
        const float4 pi = *(const float4*)(xb + (size_t)ptl*4);
        const float dx = pi.x - pj.x;
        const float dy = pi.y - pj.y;
        const float dz = pi.z - pj.z;
        const float dwv = pi.w - pj.w;
        const float ts  = (dz == 0.f) ? 1e-6f : dz;
        const float rts = __builtin_amdgcn_rcpf(ts);
        const float sxv = dx*rts*640.f;
        const float syv = dy*rts*480.f;
        *(float4*)&geo[w][half][lq][0] = make_float4(dx, dy, dz, dwv);
        *(float4*)&geo[w][half][lq][4] = make_float4(sxv, syv, fabsf(dwv), __int_as_float(j0));
        sxacc += sxv; syacc += syv;
        __builtin_amdgcn_wave_barrier();

        // h phase: this lane's row is the SAME row it just built geo for
        const size_t rowg = (size_t)b*NP + ptl;
        const float4 ee = *(const float4*)(e + rowg*DIMC + c0);
        const float ecx = ee.x + bb4.x, ecy = ee.y + bb4.y;
        const float ecz = ee.z + bb4.z, ecw = ee.w + bb4.w;
        float mxx=-INFINITY,mxy=-INFINITY,mxz=-INFINITY,mxw=-INFINITY;
        float mnx= INFINITY,mny= INFINITY,mnz= INFINITY,mnw= INFINITY;
        #pragma unroll 4
        for (int k = 0; k < KNN; ++k) {
            const float4 g0 = *(const float4*)&geo[w][half][k][0];
            const float4 g1 = *(const float4*)&geo[w][half][k][4];
            const int jj = __float_as_int(g1.w);
            const float4 gg = *(const float4*)(gbb + (size_t)jj*DIMC);

            float h0 = ecx + gg.x;
            h0 = fmaf(g0.x, w2r[0].x, h0); h0 = fmaf(g0.y, w2r[1].x, h0);
            h0 = fmaf(g0.z, w2r[2].x, h0); h0 = fmaf(g0.w, w2r[3].x, h0);
            h0 = fmaf(g1.x, w2r[4].x, h0); h0 = fmaf(g1.y, w2r[5].x, h0);
            h0 = fmaf(g1.z, w2r[6].x, h0);
            mxx = fmaxf(mxx, h0); mnx = fminf(mnx, h0);
            s1x += h0; s2x = fmaf(h0, h0, s2x);

            float h1 = ecy + gg.y;
            h1 = fmaf(g0.x, w2r[0].y, h1); h1 = fmaf(g0.y, w2r[1].y, h1);
            h1 = fmaf(g0.z, w2r[2].y, h1); h1 = fmaf(g0.w, w2r[3].y, h1);
            h1 = fmaf(g1.x, w2r[4].y, h1); h1 = fmaf(g1.y, w2r[5].y, h1);
            h1 = fmaf(g1.z, w2r[6].y, h1);
            mxy = fmaxf(mxy, h1); mny = fminf(mny, h1);
            s1y += h1; s2y = fmaf(h1, h1, s2y);

            float h2 = ecz + gg.z;
            h2 = fmaf(g0.x, w2r[0].z, h2); h2 = fmaf(g0.y, w2r[1].z, h2);
            h2 = fmaf(g0.z, w2r[2].z, h2); h2 = fmaf(g0.w, w2r[3].z, h2);
            h2 = fmaf(g1.x, w2r[4].z, h2); h2 = fmaf(g1.y, w2r[5].z, h2);
            h2 = fmaf(g1.z, w2r[6].z, h2);
            mxz = fmaxf(mxz, h2); mnz = fminf(mnz, h2);
            s1z += h2; s2z = fmaf(h2, h2, s2z);

            float h3 = ecw + gg.w;
            h3 = fmaf(g0.x, w2r[0].w, h3); h3 = fmaf(g0.y, w2r[1].w, h3);
            h3 = fmaf(g0.z, w2r[2].w, h3); h3 = fmaf(g0.w, w2r[3].w, h3);
            h3 = fmaf(g1.x, w2r[4].w, h3); h3 = fmaf(g1.y, w2r[5].w, h3);
            h3 = fmaf(g1.z, w2r[6].w, h3);
            mxw = fmaxf(mxw, h3); mnw = fminf(mnw, h3);
            s1w += h3; s2w = fmaf(h3, h3, s2w);
        }
        *(float4*)(hmaxA + rowg*DIMC + c0) = make_float4(mxx, mxy, mxz, mxw);
        *(float4*)(hminA + rowg*DIMC + c0) = make_float4(mnx, mny, mnz, mnw);
        __builtin_amdgcn_wave_barrier();   // geo reused (overwritten) next rp
    }

    // ---- speed wave-reduce -> per-block double partial ----
    #pragma unroll
    for (int off = 32; off > 0; off >>= 1) {
        sxacc += __shfl_down(sxacc, off);
        syacc += __shfl_down(syacc, off);
    }
    if (lane == 0) { swr[w*2] = sxacc; swr[w*2+1] = syacc; }

    // ---- stat partials ----
    *(float4*)&l1s[w*2 + half][c0] = make_float4(s1x, s1y, s1z, s1w);
    *(float4*)&l2s[w*2 + half][c0] = make_float4(s2x, s2y, s2z, s2w);
    __syncthreads();
    if (t < DIMC) {
        float v = 0.f;
        #pragma unroll
        for (int r = 0; r < 8; ++r) v += l1s[r][t];
        stpartT[(size_t)t*MAINBLOCKS + pb] = v;
    } else {
        const int c = t - DIMC;
        float v = 0.f;
        #pragma unroll
        for (int r = 0; r < 8; ++r) v += l2s[r][c];
        stpartT[(size_t)(DIMC + c)*MAINBLOCKS + pb] = v;
    }
    if (t == 0) {
        const double s0 = ((double)swr[0] + (double)swr[2]) + ((double)swr[4] + (double)swr[6]);
        const double s1 = ((double)swr[1] + (double)swr[3]) + ((double)swr[5] + (double)swr[7]);
        spart[(size_t)pb*2 + 0] = s0;
        spart[(size_t)pb*2 + 1] = s1;
    }
}

// ---------------- kE: stat + mean-speed reduce, per-batch affine coefficients ----------------
__global__ __launch_bounds__(256) void kE(const float* __restrict__ stpartT,
                                          const double* __restrict__ spart,
                                          const float* __restrict__ Wm,
                                          const float* __restrict__ gamma,
                                          const float* __restrict__ beta,
                                          float* __restrict__ abuf,
                                          float* __restrict__ dbuf2)
{
    __shared__ double red[256][8];   // 16 KB
    const int c = blockIdx.x;        // 0..127
    const int t = threadIdx.x;

    red[t][0] = spart[(size_t)t*2];            // sx batch0
    red[t][1] = spart[(size_t)t*2 + 1];        // sy batch0
    red[t][2] = spart[(size_t)(t+256)*2];      // sx batch1
    red[t][3] = spart[(size_t)(t+256)*2 + 1];  // sy batch1
    red[t][4] = (double)stpartT[(size_t)c*MAINBLOCKS + t];                    // S1 b0
    red[t][5] = (double)stpartT[(size_t)c*MAINBLOCKS + 256 + t];              // S1 b1
    red[t][6] = (double)stpartT[(size_t)(c + DIMC)*MAINBLOCKS + t];           // S2 b0
    red[t][7] = (double)stpartT[(size_t)(c + DIMC)*MAINBLOCKS + 256 + t];     // S2 b1
    __syncthreads();
    for (int st = 128; st > 0; st >>= 1) {
        if (t < st) {
            #pragma unroll
            for (int q = 0; q < 8; ++q) red[t][q] += red[t+st][q];
        }
        __syncthreads();
    }
    if (t == 0) {
        const double NKd = (double)(NP*KNN);
        const float ms0x = (float)(red[0][0] / NKd);
        const float ms0y = (float)(red[0][1] / NKd);
        const float ms1x = (float)(red[0][2] / NKd);
        const float ms1y = (float)(red[0][3] / NKd);
        const float wx = Wm[263*DIMC + c];
        const float wy = Wm[264*DIMC + c];
        const double cb0 = (double)fmaf(ms0x, wx, ms0y*wy);
        const double cb1 = (double)fmaf(ms1x, wx, ms1y*wy);
        const double s1b0 = red[0][4], s1b1 = red[0][5];
        const double s2b0 = red[0][6], s2b1 = red[0][7];
        const double M  = (double)MTOT;
        const double S1 = s1b0 + s1b1 + NKd*(cb0 + cb1);
        const double S2 = (s2b0 + 2.0*cb0*s1b0 + NKd*cb0*cb0)
                        + (s2b1 + 2.0*cb1*s1b1 + NKd*cb1*cb1);
        const double mu  = S1 / M;
        const double var = S2 / M - mu*mu;
        const double inv = 1.0 / sqrt(var + 1e-5);
        const double a  = (double)gamma[c] * inv;
        const double db = (double)beta[c] - mu*a;
        abuf[c] = (float)a;
        dbuf2[c]        = (float)(db + cb0*a);
        dbuf2[DIMC + c] = (float)(db + cb1*a);
    }
}

// ---------------- kF: normalize + relu on the pre-reduced K-extremes ----------------
__global__ __launch_bounds__(256) void kF(const float* __restrict__ hmaxA,
                                          const float* __restrict__ hminA,
                                          const float* __restrict__ abuf,
                                          const float* __restrict__ dbuf2,
                                          float* __restrict__ out)
{
    const int gid = blockIdx.x*256 + threadIdx.x;
    const int row = gid >> 6;
    const int c0  = (gid & 63)*2;
    const int b   = row >> 12;
    const size_t off = (size_t)row*DIMC + c0;
    const float2 mx = *(const float2*)(hmaxA + off);
    const float2 mn = *(const float2*)(hminA + off);
    const float a0 = abuf[c0],  a1 = abuf[c0+1];
    const float d0 = dbuf2[b*DIMC + c0], d1 = dbuf2[b*DIMC + c0 + 1];
    const float h0 = (a0 >= 0.f) ? mx.x : mn.x;
    const float h1 = (a1 >= 0.f) ? mx.y : mn.y;
    float2 o;
    o.x = fmaxf(fmaf(h0, a0, d0), 0.0f);
    o.y = fmaxf(fmaf(h1, a1, d1), 0.0f);
    *(float2*)(out + off) = o;
}

extern "C" void kernel_launch(void* const* d_in, const int* in_sizes, int n_in,
                              void* d_out, int out_size, void* d_ws, size_t ws_size,
                              hipStream_t stream)
{
    const float* xyzp  = (const float*)d_in[0];
    const float* feat  = (const float*)d_in[1];
    const float* Wm    = (const float*)d_in[2];
    const float* bbias = (const float*)d_in[3];
    const float* gamma = (const float*)d_in[4];
    const float* beta  = (const float*)d_in[5];

    char* ws = (char*)d_ws;
    const size_t MB = 1u << 20;
    float*  g       = (float*) (ws + 1*MB);          // 4 MB
    float*  e       = (float*) (ws + 5*MB);          // 4 MB
    float*  hmaxA   = (float*) (ws + 9*MB);          // 4 MB
    float*  hminA   = (float*) (ws + 13*MB);         // 4 MB
    double* spart   = (double*)(ws + 17*MB);         // 8 KB (512 x double2)
    float*  abuf    = (float*) (ws + 17*MB + 65536); // 512 B
    float*  dbuf2   = (float*) (ws + 17*MB + 66560); // 1 KB
    float*  stpartT = (float*) (ws + 18*MB);         // 512 KB (256 x 512)
    uint4*  featb   = (uint4*) (ws + 19*MB);         // 2 MB  (bf16 fragments)
    uint4*  Wb      = (uint4*) (ws + 21*MB);         // 64 KB (bf16 fragments)

    kC  <<<528, 256, 0, stream>>>(feat, Wm, featb, Wb);
    k1m <<<512, 256, 0, stream>>>((const bf16x8*)featb, (const bf16x8*)Wb, e, g);
    k2  <<<K2BLOCKS, 256, 0, stream>>>(xyzp, e, g, Wm, bbias, spart, hmaxA, hminA, stpartT);
    kE  <<<DIMC, 256, 0, stream>>>(stpartT, spart, Wm, gamma, beta, abuf, dbuf2);
    kF  <<<(NROWS*64)/256, 256, 0, stream>>>(hmaxA, hminA, abuf, dbuf2, (float*)d_out);
}

// Round 11
// 47.940 us; speedup vs baseline: 1.2100x; 1.0450x over previous
//
#include <hip/hip_runtime.h>
#include <math.h>

#define NB   2
#define NP   4096
#define KNN  32
#define DIMC 128
#define NROWS (NB*NP)          // 8192
#define MTOT  (NB*NP*KNN)      // 262144
#define K2BLOCKS 512           // 16 points each (4 per wave)
#define MAINBLOCKS 512

static constexpr float R2 = 0.04f;

typedef short bf16x8 __attribute__((ext_vector_type(8)));   // 8 bf16 (4 VGPRs)
typedef float f32x4  __attribute__((ext_vector_type(4)));   // MFMA accumulator

__device__ __forceinline__ unsigned f2bf(float f) {         // RNE bf16 round
    unsigned u = __float_as_uint(f);
    return ((u + 0x7FFFu + ((u >> 16) & 1u)) >> 16);
}
__device__ __forceinline__ float bf2f(unsigned us) {
    return __uint_as_float(us << 16);
}
__device__ __forceinline__ bf16x8 pack8(float4 v0, float4 v1) {
    union { unsigned u[4]; bf16x8 b; } o;
    o.u[0] = f2bf(v0.x) | (f2bf(v0.y) << 16);
    o.u[1] = f2bf(v0.z) | (f2bf(v0.w) << 16);
    o.u[2] = f2bf(v1.x) | (f2bf(v1.y) << 16);
    o.u[3] = f2bf(v1.z) | (f2bf(v1.w) << 16);
    return o.b;
}

// ---------------- k1m: e|g = feat @ [W0|W1] via MFMA bf16, fused packing ----------------
// Grid 512 row-tiles; block = 16 rows x 256 cols; wave w owns col-tiles w*4..w*4+3.
// A fragments packed inline from 2 coalesced b128/lane; W fragments packed inline
// from strided b32 (each instr touches ~4 cache lines of the 128 KB L1/L2-hot W).
// D layout (m89-verified): col=lane&15, row=(lane>>4)*4+reg.
__global__ __launch_bounds__(256) void k1m(const float* __restrict__ feat,
                                           const float* __restrict__ Wm,
                                           float* __restrict__ e,
                                           float* __restrict__ g)
{
    const int t    = threadIdx.x;
    const int w    = t >> 6;
    const int lane = t & 63;
    const int rt   = blockIdx.x;          // rows rt*16..rt*16+15
    const int r    = lane & 15;
    const int kg   = lane >> 4;           // 0..3

    // A fragments: lane holds A[rt*16+r][ks*32 + kg*8 + 0..7]
    bf16x8 af[4];
    const float* arow = feat + (size_t)(rt*16 + r)*DIMC + kg*8;
    #pragma unroll
    for (int ks = 0; ks < 4; ++ks) {
        const float4 v0 = *(const float4*)(arow + ks*32);
        const float4 v1 = *(const float4*)(arow + ks*32 + 4);
        af[ks] = pack8(v0, v1);
    }

    // wave w -> cols w*64 .. w*64+63 : (w>>1) selects W0/e vs W1/g, (w&1) the 64-col half
    const float* wcol = Wm + (size_t)(w >> 1)*128*DIMC + (w & 1)*64 + r;
    float* dst = (w >> 1) ? g : e;
    const int ccb = (w & 1)*64 + r;

    #pragma unroll
    for (int ct = 0; ct < 4; ++ct) {
        f32x4 acc = {0.f, 0.f, 0.f, 0.f};
        #pragma unroll
        for (int ks = 0; ks < 4; ++ks) {
            // B fragment: lane holds B[ks*32+kg*8+j][ct*16 + r], j=0..7
            const float* bsrc = wcol + (size_t)(ks*32 + kg*8)*DIMC + ct*16;
            float bv[8];
            #pragma unroll
            for (int j = 0; j < 8; ++j) bv[j] = bsrc[(size_t)j*DIMC];
            const bf16x8 bb = pack8(make_float4(bv[0],bv[1],bv[2],bv[3]),
                                    make_float4(bv[4],bv[5],bv[6],bv[7]));
            acc = __builtin_amdgcn_mfma_f32_16x16x32_bf16(af[ks], bb, acc, 0, 0, 0);
        }
        #pragma unroll
        for (int reg = 0; reg < 4; ++reg)
            dst[(size_t)(rt*16 + kg*4 + reg)*DIMC + ccb + ct*16] = acc[reg];
    }
}

// ---------------- k2: mask + extract + geo + h (min/max over K) + stat partials ----------------
// hmax/hmin packed bf16x8 into one uint4 per (row, channel-quad).
__global__ __launch_bounds__(256) void k2(const float* __restrict__ xyzp,
                                          const float* __restrict__ e,
                                          const float* __restrict__ g,
                                          const float* __restrict__ Wm,
                                          const float* __restrict__ bbias,
                                          double* __restrict__ spart,
                                          uint4* __restrict__ hmm,
                                          float* __restrict__ stpartT)
{
    __shared__ float xy[NP*2];                 // 32 KB
    __shared__ int   idxrow[16*KNN];           // 2 KB
    __shared__ float geo[4][2][KNN][8];        // 8 KB
    __shared__ float l1s[8][DIMC];             // 4 KB
    __shared__ float l2s[8][DIMC];             // 4 KB
    __shared__ float swr[8];

    const int bx  = blockIdx.x;
    const int xcd = bx & 7;
    const int pb  = ((xcd >> 2) << 8) + (bx >> 3)*4 + (xcd & 3);  // bijective: batch b -> 4 XCDs
    const int b   = pb >> 8;
    const int p0  = (pb & 255) * 16;

    const int t    = threadIdx.x;
    const int w    = t >> 6;
    const int lane = t & 63;
    const float* xb = xyzp + (size_t)b*NP*4;

    for (int q = t; q < NP; q += 256) {
        const float4 v = *(const float4*)(xb + (size_t)q*4);
        xy[q*2 + 0] = v.x;
        xy[q*2 + 1] = v.y;
    }
    __syncthreads();

    // ---- mask build (contract off to match numpy d2 exactly) ----
    const int pl0 = p0 + w*4;
    unsigned long long wacc[4] = {0ULL, 0ULL, 0ULL, 0ULL};
    {
#pragma clang fp contract(off)
        float xi[4], yi[4];
        #pragma unroll
        for (int p = 0; p < 4; ++p) { xi[p] = xy[(pl0+p)*2]; yi[p] = xy[(pl0+p)*2+1]; }
        for (int c = 0; c < NP/64; ++c) {
            const float2 q = *(const float2*)(xy + (size_t)(c*64 + lane)*2);
            const bool keep = (lane == c);
            #pragma unroll
            for (int p = 0; p < 4; ++p) {
                const float dx = xi[p] - q.x;
                const float dy = yi[p] - q.y;
                const float dx2 = dx*dx;
                const float dy2 = dy*dy;
                const unsigned long long m = __ballot((dx2 + dy2) < R2);
                if (keep) wacc[p] = m;        // lane l keeps word l (j in [64l, 64l+64))
            }
        }
    }

    // ---- extraction: 32 smallest hit indices per point ----
    #pragma unroll
    for (int p = 0; p < 4; ++p) {
        unsigned long long wd = wacc[p];
        const int cnt = __popcll(wd);
        int pre = cnt;
        #pragma unroll
        for (int off = 1; off < 64; off <<= 1) {
            const int tv = __shfl_up(pre, off);
            if (lane >= off) pre += tv;
        }
        const int total = __shfl(pre, 63);
        int slot = pre - cnt;                 // exclusive prefix
        unsigned long long ww = wd;
        while (ww != 0ULL && slot < KNN) {
            const int bpos = __builtin_ctzll(ww);
            idxrow[(w*4 + p)*KNN + slot] = lane*64 + bpos;
            ww &= ww - 1ULL;
            ++slot;
        }
        const int iself = pl0 + p;
        for (int kk = min(total, KNN) + lane; kk < KNN; kk += 64)
            idxrow[(w*4 + p)*KNN + kk] = iself;
    }

    // ---- per-lane channel constants ----
    const int half = lane >> 5;
    const int lq   = lane & 31;
    const int c0   = lq * 4;
    float4 w2r[7];
    #pragma unroll
    for (int r = 0; r < 7; ++r)
        w2r[r] = *(const float4*)(Wm + (size_t)(256 + r)*DIMC + c0);
    const float4 bb4 = *(const float4*)(bbias + c0);

    float s1x=0.f,s1y=0.f,s1z=0.f,s1w=0.f;
    float s2x=0.f,s2y=0.f,s2z=0.f,s2w=0.f;
    float sxacc = 0.f, syacc = 0.f;
    const float* gbb = g + (size_t)b*NP*DIMC + c0;

    for (int rp = 0; rp < 2; ++rp) {
        // geo phase: lane handles pair (row = w*4+rp*2+half, k = lq)
        const int rloc = w*4 + rp*2 + half;
        const int ptl  = p0 + rloc;
        const int j0   = idxrow[rloc*KNN + lq];
        const float4 pj = *(const float4*)(xb + (size_t)j0*4);
        const float4 pi = *(const float4*)(xb + (size_t)ptl*4);
        const float dx = pi.x - pj.x;
        const float dy = pi.y - pj.y;
        const float dz = pi.z - pj.z;
        const float dwv = pi.w - pj.w;
        const float ts  = (dz == 0.f) ? 1e-6f : dz;
        const float rts = __builtin_amdgcn_rcpf(ts);
        const float sxv = dx*rts*640.f;
        const float syv = dy*rts*480.f;
        *(float4*)&geo[w][half][lq][0] = make_float4(dx, dy, dz, dwv);
        *(float4*)&geo[w][half][lq][4] = make_float4(sxv, syv, fabsf(dwv), __int_as_float(j0));
        sxacc += sxv; syacc += syv;
        __builtin_amdgcn_wave_barrier();

        // h phase: this lane's row is the SAME row it just built geo for
        const size_t rowg = (size_t)b*NP + ptl;
        const float4 ee = *(const float4*)(e + rowg*DIMC + c0);
        const float ecx = ee.x + bb4.x, ecy = ee.y + bb4.y;
        const float ecz = ee.z + bb4.z, ecw = ee.w + bb4.w;
        float mxx=-INFINITY,mxy=-INFINITY,mxz=-INFINITY,mxw=-INFINITY;
        float mnx= INFINITY,mny= INFINITY,mnz= INFINITY,mnw= INFINITY;
        #pragma unroll 4
        for (int k = 0; k < KNN; ++k) {
            const float4 g0 = *(const float4*)&geo[w][half][k][0];
            const float4 g1 = *(const float4*)&geo[w][half][k][4];
            const int jj = __float_as_int(g1.w);
            const float4 gg = *(const float4*)(gbb + (size_t)jj*DIMC);

            float h0 = ecx + gg.x;
            h0 = fmaf(g0.x, w2r[0].x, h0); h0 = fmaf(g0.y, w2r[1].x, h0);
            h0 = fmaf(g0.z, w2r[2].x, h0); h0 = fmaf(g0.w, w2r[3].x, h0);
            h0 = fmaf(g1.x, w2r[4].x, h0); h0 = fmaf(g1.y, w2r[5].x, h0);
            h0 = fmaf(g1.z, w2r[6].x, h0);
            mxx = fmaxf(mxx, h0); mnx = fminf(mnx, h0);
            s1x += h0; s2x = fmaf(h0, h0, s2x);

            float h1 = ecy + gg.y;
            h1 = fmaf(g0.x, w2r[0].y, h1); h1 = fmaf(g0.y, w2r[1].y, h1);
            h1 = fmaf(g0.z, w2r[2].y, h1); h1 = fmaf(g0.w, w2r[3].y, h1);
            h1 = fmaf(g1.x, w2r[4].y, h1); h1 = fmaf(g1.y, w2r[5].y, h1);
            h1 = fmaf(g1.z, w2r[6].y, h1);
            mxy = fmaxf(mxy, h1); mny = fminf(mny, h1);
            s1y += h1; s2y = fmaf(h1, h1, s2y);

            float h2 = ecz + gg.z;
            h2 = fmaf(g0.x, w2r[0].z, h2); h2 = fmaf(g0.y, w2r[1].z, h2);
            h2 = fmaf(g0.z, w2r[2].z, h2); h2 = fmaf(g0.w, w2r[3].z, h2);
            h2 = fmaf(g1.x, w2r[4].z, h2); h2 = fmaf(g1.y, w2r[5].z, h2);
            h2 = fmaf(g1.z, w2r[6].z, h2);
            mxz = fmaxf(mxz, h2); mnz = fminf(mnz, h2);
            s1z += h2; s2z = fmaf(h2, h2, s2z);

            float h3 = ecw + gg.w;
            h3 = fmaf(g0.x, w2r[0].w, h3); h3 = fmaf(g0.y, w2r[1].w, h3);
            h3 = fmaf(g0.z, w2r[2].w, h3); h3 = fmaf(g0.w, w2r[3].w, h3);
            h3 = fmaf(g1.x, w2r[4].w, h3); h3 = fmaf(g1.y, w2r[5].w, h3);
            h3 = fmaf(g1.z, w2r[6].w, h3);
            mxw = fmaxf(mxw, h3); mnw = fminf(mnw, h3);
            s1w += h3; s2w = fmaf(h3, h3, s2w);
        }
        uint4 o;
        o.x = f2bf(mxx) | (f2bf(mxy) << 16);
        o.y = f2bf(mxz) | (f2bf(mxw) << 16);
        o.z = f2bf(mnx) | (f2bf(mny) << 16);
        o.w = f2bf(mnz) | (f2bf(mnw) << 16);
        hmm[rowg*32 + lq] = o;
        __builtin_amdgcn_wave_barrier();   // geo reused (overwritten) next rp
    }

    // ---- speed wave-reduce -> per-block double partial ----
    #pragma unroll
    for (int off = 32; off > 0; off >>= 1) {
        sxacc += __shfl_down(sxacc, off);
        syacc += __shfl_down(syacc, off);
    }
    if (lane == 0) { swr[w*2] = sxacc; swr[w*2+1] = syacc; }

    // ---- stat partials ----
    *(float4*)&l1s[w*2 + half][c0] = make_float4(s1x, s1y, s1z, s1w);
    *(float4*)&l2s[w*2 + half][c0] = make_float4(s2x, s2y, s2z, s2w);
    __syncthreads();
    if (t < DIMC) {
        float v = 0.f;
        #pragma unroll
        for (int r = 0; r < 8; ++r) v += l1s[r][t];
        stpartT[(size_t)t*MAINBLOCKS + pb] = v;
    } else {
        const int c = t - DIMC;
        float v = 0.f;
        #pragma unroll
        for (int r = 0; r < 8; ++r) v += l2s[r][c];
        stpartT[(size_t)(DIMC + c)*MAINBLOCKS + pb] = v;
    }
    if (t == 0) {
        const double s0 = ((double)swr[0] + (double)swr[2]) + ((double)swr[4] + (double)swr[6]);
        const double s1 = ((double)swr[1] + (double)swr[3]) + ((double)swr[5] + (double)swr[7]);
        spart[(size_t)pb*2 + 0] = s0;
        spart[(size_t)pb*2 + 1] = s1;
    }
}

// ---------------- kE: stat + mean-speed reduce, per-batch affine coefficients ----------------
__global__ __launch_bounds__(256) void kE(const float* __restrict__ stpartT,
                                          const double* __restrict__ spart,
                                          const float* __restrict__ Wm,
                                          const float* __restrict__ gamma,
                                          const float* __restrict__ beta,
                                          float* __restrict__ abuf,
                                          float* __restrict__ dbuf2)
{
    __shared__ double red[256][8];   // 16 KB
    const int c = blockIdx.x;        // 0..127
    const int t = threadIdx.x;

    red[t][0] = spart[(size_t)t*2];            // sx batch0
    red[t][1] = spart[(size_t)t*2 + 1];        // sy batch0
    red[t][2] = spart[(size_t)(t+256)*2];      // sx batch1
    red[t][3] = spart[(size_t)(t+256)*2 + 1];  // sy batch1
    red[t][4] = (double)stpartT[(size_t)c*MAINBLOCKS + t];                    // S1 b0
    red[t][5] = (double)stpartT[(size_t)c*MAINBLOCKS + 256 + t];              // S1 b1
    red[t][6] = (double)stpartT[(size_t)(c + DIMC)*MAINBLOCKS + t];           // S2 b0
    red[t][7] = (double)stpartT[(size_t)(c + DIMC)*MAINBLOCKS + 256 + t];     // S2 b1
    __syncthreads();
    for (int st = 128; st > 0; st >>= 1) {
        if (t < st) {
            #pragma unroll
            for (int q = 0; q < 8; ++q) red[t][q] += red[t+st][q];
        }
        __syncthreads();
    }
    if (t == 0) {
        const double NKd = (double)(NP*KNN);
        const float ms0x = (float)(red[0][0] / NKd);
        const float ms0y = (float)(red[0][1] / NKd);
        const float ms1x = (float)(red[0][2] / NKd);
        const float ms1y = (float)(red[0][3] / NKd);
        const float wx = Wm[263*DIMC + c];
        const float wy = Wm[264*DIMC + c];
        const double cb0 = (double)fmaf(ms0x, wx, ms0y*wy);
        const double cb1 = (double)fmaf(ms1x, wx, ms1y*wy);
        const double s1b0 = red[0][4], s1b1 = red[0][5];
        const double s2b0 = red[0][6], s2b1 = red[0][7];
        const double M  = (double)MTOT;
        const double S1 = s1b0 + s1b1 + NKd*(cb0 + cb1);
        const double S2 = (s2b0 + 2.0*cb0*s1b0 + NKd*cb0*cb0)
                        + (s2b1 + 2.0*cb1*s1b1 + NKd*cb1*cb1);
        const double mu  = S1 / M;
        const double var = S2 / M - mu*mu;
        const double inv = 1.0 / sqrt(var + 1e-5);
        const double a  = (double)gamma[c] * inv;
        const double db = (double)beta[c] - mu*a;
        abuf[c] = (float)a;
        dbuf2[c]        = (float)(db + cb0*a);
        dbuf2[DIMC + c] = (float)(db + cb1*a);
    }
}

// ---------------- kF: normalize + relu on the packed K-extremes ----------------
__global__ __launch_bounds__(256) void kF(const uint4* __restrict__ hmm,
                                          const float* __restrict__ abuf,
                                          const float* __restrict__ dbuf2,
                                          float* __restrict__ out)
{
    const int gid = blockIdx.x*256 + threadIdx.x;   // 0..262143: 4 channels each
    const int row = gid >> 5;
    const int lq  = gid & 31;
    const int c0  = lq * 4;
    const int b   = row >> 12;
    const uint4 p = hmm[(size_t)row*32 + lq];
    const float4 a4 = *(const float4*)(abuf + c0);
    const float4 d4 = *(const float4*)(dbuf2 + b*DIMC + c0);
    const float mx0 = bf2f(p.x & 0xFFFFu), mx1 = bf2f(p.x >> 16);
    const float mx2 = bf2f(p.y & 0xFFFFu), mx3 = bf2f(p.y >> 16);
    const float mn0 = bf2f(p.z & 0xFFFFu), mn1 = bf2f(p.z >> 16);
    const float mn2 = bf2f(p.w & 0xFFFFu), mn3 = bf2f(p.w >> 16);
    float4 o;
    o.x = fmaxf(fmaf((a4.x >= 0.f) ? mx0 : mn0, a4.x, d4.x), 0.f);
    o.y = fmaxf(fmaf((a4.y >= 0.f) ? mx1 : mn1, a4.y, d4.y), 0.f);
    o.z = fmaxf(fmaf((a4.z >= 0.f) ? mx2 : mn2, a4.z, d4.z), 0.f);
    o.w = fmaxf(fmaf((a4.w >= 0.f) ? mx3 : mn3, a4.w, d4.w), 0.f);
    *(float4*)(out + (size_t)row*DIMC + c0) = o;
}

extern "C" void kernel_launch(void* const* d_in, const int* in_sizes, int n_in,
                              void* d_out, int out_size, void* d_ws, size_t ws_size,
                              hipStream_t stream)
{
    const float* xyzp  = (const float*)d_in[0];
    const float* feat  = (const float*)d_in[1];
    const float* Wm    = (const float*)d_in[2];
    const float* bbias = (const float*)d_in[3];
    const float* gamma = (const float*)d_in[4];
    const float* beta  = (const float*)d_in[5];

    char* ws = (char*)d_ws;
    const size_t MB = 1u << 20;
    float*  g       = (float*) (ws + 1*MB);          // 4 MB
    float*  e       = (float*) (ws + 5*MB);          // 4 MB
    uint4*  hmm     = (uint4*) (ws + 9*MB);          // 4 MB (bf16 max|min packed)
    double* spart   = (double*)(ws + 17*MB);         // 8 KB (512 x double2)
    float*  abuf    = (float*) (ws + 17*MB + 65536); // 512 B
    float*  dbuf2   = (float*) (ws + 17*MB + 66560); // 1 KB
    float*  stpartT = (float*) (ws + 18*MB);         // 512 KB (256 x 512)

    k1m <<<512, 256, 0, stream>>>(feat, Wm, e, g);
    k2  <<<K2BLOCKS, 256, 0, stream>>>(xyzp, e, g, Wm, bbias, spart, hmm, stpartT);
    kE  <<<DIMC, 256, 0, stream>>>(stpartT, spart, Wm, gamma, beta, abuf, dbuf2);
    kF  <<<(NROWS*32)/256, 256, 0, stream>>>(hmm, abuf, dbuf2, (float*)d_out);
}